// Round 12
// baseline (172.528 us; speedup 1.0000x reference)
//
#include <hip/hip_runtime.h>
#include <hip/hip_bf16.h>

typedef __attribute__((ext_vector_type(8))) unsigned short ushort8;
typedef __attribute__((ext_vector_type(8))) __bf16 bf16x8;
typedef __attribute__((ext_vector_type(4))) float f32x4;
typedef __attribute__((ext_vector_type(4))) float floatx4;

__device__ __forceinline__ unsigned short f2bf(float f) {
    unsigned u = __builtin_bit_cast(unsigned, f);
    u += 0x7fffu + ((u >> 16) & 1u);   // RNE
    return (unsigned short)(u >> 16);
}
__device__ __forceinline__ float bf2f(unsigned short h) {
    unsigned u = ((unsigned)h) << 16;
    return __builtin_bit_cast(float, u);
}

__device__ __forceinline__ void gload_lds16(const void* g, void* l) {
    __builtin_amdgcn_global_load_lds(
        (const __attribute__((address_space(1))) void*)g,
        (__attribute__((address_space(3))) void*)l,
        16, 0, 0);
}

#define BAR()   asm volatile("s_barrier" ::: "memory")
#define VMW0()  asm volatile("s_waitcnt vmcnt(0)" ::: "memory")

// ===== merged prep: 3 f32->bf16 converts + Weff, one dispatch ============
// blocks [0,8192)      : cvt x      (2097152 x 8 elems)
// blocks [8192,12288)  : cvt W0     (1048576 x 8)
// blocks [12288,14336) : cvt W1     (524288 x 8)
// blocks [14336,15360) : weff row o = b - 14336
__global__ __launch_bounds__(256) void prep_kernel(
        const float* __restrict__ x,   unsigned short* __restrict__ xb,
        const float* __restrict__ W0,  unsigned short* __restrict__ w0b,
        const float* __restrict__ W1,  unsigned short* __restrict__ w1b,
        const float* __restrict__ fcW, const float* __restrict__ lng,
        const float* __restrict__ lnb, const float* __restrict__ fcb,
        unsigned short* __restrict__ weff, float* __restrict__ cc,
        float* __restrict__ wsum) {
    const int b = blockIdx.x;
    const int tid = threadIdx.x;
    __shared__ float red[4], redw[4];

    if (b < 14336) {
        const float* in; unsigned short* out; int i;
        if (b < 8192)       { in = x;  out = xb;  i = b * 256 + tid; }
        else if (b < 12288) { in = W0; out = w0b; i = (b - 8192) * 256 + tid; }
        else                { in = W1; out = w1b; i = (b - 12288) * 256 + tid; }
        floatx4 a = ((const floatx4*)in)[2 * i];
        floatx4 c = ((const floatx4*)in)[2 * i + 1];
        ushort8 o;
#pragma unroll
        for (int j = 0; j < 4; ++j) { o[j] = f2bf(a[j]); o[4 + j] = f2bf(c[j]); }
        ((ushort8*)out)[i] = o;
        return;
    }

    const int o = b - 14336;
    if (o >= 1000) {
        ushort8 z = {0, 0, 0, 0, 0, 0, 0, 0};
        ((ushort8*)(weff + (size_t)o * 2048))[tid] = z;
        if (tid == 0) { cc[o] = 0.f; wsum[o] = 0.f; }
        return;
    }
    const float* wrow = fcW + (size_t)o * 4096;
    int j0 = tid * 8;
    floatx4 wa  = *(const floatx4*)(wrow + j0);
    floatx4 wb  = *(const floatx4*)(wrow + j0 + 4);
    floatx4 wa2 = *(const floatx4*)(wrow + 2048 + j0);
    floatx4 wb2 = *(const floatx4*)(wrow + 2048 + j0 + 4);
    floatx4 ga  = *(const floatx4*)(lng + j0);
    floatx4 gb  = *(const floatx4*)(lng + j0 + 4);
    floatx4 ga2 = *(const floatx4*)(lng + 2048 + j0);
    floatx4 gb2 = *(const floatx4*)(lng + 2048 + j0 + 4);
    floatx4 ba  = *(const floatx4*)(lnb + j0);
    floatx4 bb  = *(const floatx4*)(lnb + j0 + 4);
    floatx4 ba2 = *(const floatx4*)(lnb + 2048 + j0);
    floatx4 bb2 = *(const floatx4*)(lnb + 2048 + j0 + 4);
    ushort8 o8;
    float acc = 0.f, ws = 0.f;
#pragma unroll
    for (int j = 0; j < 4; ++j) {
        o8[j] = f2bf(ga[j] * wa[j] + ga2[j] * wa2[j]);
        acc += ba[j] * wa[j] + ba2[j] * wa2[j];
        ws  += bf2f(o8[j]);
        o8[4 + j] = f2bf(gb[j] * wb[j] + gb2[j] * wb2[j]);
        acc += bb[j] * wb[j] + bb2[j] * wb2[j];
        ws  += bf2f(o8[4 + j]);
    }
    ((ushort8*)(weff + (size_t)o * 2048))[tid] = o8;
#pragma unroll
    for (int d = 32; d; d >>= 1) { acc += __shfl_down(acc, d); ws += __shfl_down(ws, d); }
    if ((tid & 63) == 0) { red[tid >> 6] = acc; redw[tid >> 6] = ws; }
    __syncthreads();
    if (tid == 0) {
        cc[o] = fcb[o] + red[0] + red[1] + red[2] + red[3];
        wsum[o] = redw[0] + redw[1] + redw[2] + redw[3];
    }
}

// == reg-pipelined bf16 GEMM: C[M,N] = A[M,K]*B[N,K]^T, BK=64, 3 LDS bufs ==
// BM=128, BN=64*NJ, 512 threads (8 waves 2M x 4N), per-wave C = 64 x 16*NJ.
// Cross-tile register double-buffer; counted vmcnt keeps one tile's stage
// loads in flight across the barrier. 128B rows, byte ^= (row&7)<<4 swizzle
// (0 conflicts measured). Best-known structure (r6: gemm1 78us / 880 TF).
// EPI 0: bf16 out = tanh(acc + bias0[n] + bias1[n]), stride N
// EPI 2: EPI 0 + per-row LN partial sums {S,S2} of the ROUNDED bf16 values,
//        reduced block-wide (shfl over fr, LDS over wn) -> psum[row*8+bx]
// EPI 1: f32 out = r*(acc - mu*wsum[col]) + bias0[col], mu/r computed
//        inline from the 8 psum partials per row (ln_stats eliminated)
template <int EPI, int NJ>
__global__ __launch_bounds__(512, 2) void gemm_rp(const unsigned short* __restrict__ A,
                                                  const unsigned short* __restrict__ B,
                                                  int M, int N, int K,
                                                  const float* __restrict__ bias0,
                                                  const float* __restrict__ bias1,
                                                  void* __restrict__ Cout, int ncols,
                                                  float2* __restrict__ psum,
                                                  const float* __restrict__ wsum) {
    extern __shared__ char smem[];
    constexpr int BUFSZ = 16384 + NJ * 8192;   // A (16KB) + B (NJ*8KB), BK=64
    const int tid = threadIdx.x;
    const int lane = tid & 63, wid = tid >> 6;
    const int wm = wid >> 2, wn = wid & 3;      // 2 x 4 wave grid
    const int fr = lane & 15, g = lane >> 4;

    // XCD-aware bijective swizzle (nwg % 8 == 0 for all our launches)
    const int nwg = gridDim.x * gridDim.y;
    const int fid = blockIdx.y * gridDim.x + blockIdx.x;
    const int cpx = nwg >> 3;
    const int sw = (fid & 7) * cpx + (fid >> 3);
    const int bx = sw % gridDim.x, by = sw / gridDim.x;
    const int row0 = by * 128, col0 = bx * (64 * NJ);

    const int tg = tid >> 3;
    const int tcE = ((tid & 7) ^ (tg & 7)) * 8;

    auto stage = [&](int kt, char* buf) {
#pragma unroll
        for (int r = 0; r < 2; ++r)
            gload_lds16(A + (size_t)(row0 + r * 64 + tg) * K + kt * 64 + tcE,
                        buf + r * 8192 + wid * 1024);
#pragma unroll
        for (int rr = 0; rr < NJ; ++rr)
            gload_lds16(B + (size_t)(col0 + rr * 64 + tg) * K + kt * 64 + tcE,
                        buf + 16384 + rr * 8192 + wid * 1024);
    };

    const int xorv = (fr & 7) << 4;
    auto readFrags = [&](bf16x8 (&fa)[4][2], bf16x8 (&fb)[NJ][2], const char* buf) {
#pragma unroll
        for (int m = 0; m < 4; ++m)
#pragma unroll
            for (int kh = 0; kh < 2; ++kh)
                fa[m][kh] = __builtin_bit_cast(bf16x8, *(const ushort8*)(
                    buf + (wm * 64 + m * 16 + fr) * 128 + ((kh * 64 + g * 16) ^ xorv)));
#pragma unroll
        for (int n = 0; n < NJ; ++n)
#pragma unroll
            for (int kh = 0; kh < 2; ++kh)
                fb[n][kh] = __builtin_bit_cast(bf16x8, *(const ushort8*)(
                    buf + 16384 + (wn * (16 * NJ) + n * 16 + fr) * 128 + ((kh * 64 + g * 16) ^ xorv)));
    };

    f32x4 acc[4][NJ];
#pragma unroll
    for (int i = 0; i < 4; ++i)
#pragma unroll
        for (int j = 0; j < NJ; ++j) acc[i][j] = f32x4{0.f, 0.f, 0.f, 0.f};

    auto domfma = [&](bf16x8 (&fa)[4][2], bf16x8 (&fb)[NJ][2]) {
        __builtin_amdgcn_s_setprio(1);
#pragma unroll
        for (int m = 0; m < 4; ++m)
#pragma unroll
            for (int n = 0; n < NJ; ++n)
#pragma unroll
                for (int kh = 0; kh < 2; ++kh)
                    acc[m][n] = __builtin_amdgcn_mfma_f32_16x16x32_bf16(fa[m][kh], fb[n][kh], acc[m][n], 0, 0, 0);
        __builtin_amdgcn_s_setprio(0);
    };

    bf16x8 aX[4][2], bX[NJ][2], aY[4][2], bY[NJ][2];

    stage(0, smem); stage(1, smem + BUFSZ);
    if constexpr (NJ == 4) { asm volatile("s_waitcnt vmcnt(6)" ::: "memory"); }
    else                   { asm volatile("s_waitcnt vmcnt(4)" ::: "memory"); }
    BAR();
    readFrags(aX, bX, smem);

    const int NT = K >> 6;   // always even here
    for (int t = 0; t < NT; t += 2) {
        if (t + 2 < NT) {
            stage(t + 2, smem + ((t + 2) % 3) * BUFSZ);
            if constexpr (NJ == 4) { asm volatile("s_waitcnt vmcnt(6)" ::: "memory"); }
            else                   { asm volatile("s_waitcnt vmcnt(4)" ::: "memory"); }
        } else {
            VMW0();
        }
        BAR();
        readFrags(aY, bY, smem + ((t + 1) % 3) * BUFSZ);
        domfma(aX, bX);

        if (t + 2 < NT) {
            if (t + 3 < NT) {
                stage(t + 3, smem + ((t + 3) % 3) * BUFSZ);
                if constexpr (NJ == 4) { asm volatile("s_waitcnt vmcnt(6)" ::: "memory"); }
                else                   { asm volatile("s_waitcnt vmcnt(4)" ::: "memory"); }
            } else {
                VMW0();
            }
            BAR();
            readFrags(aX, bX, smem + ((t + 2) % 3) * BUFSZ);
        }
        domfma(aY, bY);
    }

    // ---- epilogue ----
    if constexpr (EPI == 0 || EPI == 2) {
        float s1[4][4], s2[4][4];   // [i][r] row-partial sums (EPI 2)
        if constexpr (EPI == 2) {
#pragma unroll
            for (int i = 0; i < 4; ++i)
#pragma unroll
                for (int r = 0; r < 4; ++r) { s1[i][r] = 0.f; s2[i][r] = 0.f; }
        }
#pragma unroll
        for (int i = 0; i < 4; ++i) {
            int rbase = row0 + wm * 64 + i * 16 + g * 4;
#pragma unroll
            for (int j = 0; j < NJ; ++j) {
                int col = col0 + wn * (16 * NJ) + j * 16 + fr;
                float bsum = bias0[col] + bias1[col];
                unsigned short* O = (unsigned short*)Cout;
#pragma unroll
                for (int r = 0; r < 4; ++r) {
                    unsigned short us = f2bf(tanhf(acc[i][j][r] + bsum));
                    O[(size_t)(rbase + r) * N + col] = us;
                    if constexpr (EPI == 2) {
                        float vb = bf2f(us);
                        s1[i][r] += vb; s2[i][r] += vb * vb;
                    }
                }
            }
        }
        if constexpr (EPI == 2) {
            __syncthreads();                      // staging LDS now dead; reuse
            float2* wsums = (float2*)smem;        // [128 rows][4 wn]
#pragma unroll
            for (int i = 0; i < 4; ++i)
#pragma unroll
                for (int r = 0; r < 4; ++r) {
                    float a = s1[i][r], b = s2[i][r];
#pragma unroll
                    for (int mk = 1; mk < 16; mk <<= 1) {
                        a += __shfl_xor(a, mk);
                        b += __shfl_xor(b, mk);
                    }
                    if (fr == 0)
                        wsums[(wm * 64 + i * 16 + g * 4 + r) * 4 + wn] = make_float2(a, b);
                }
            __syncthreads();
            if (tid < 128) {
                float2 p0 = wsums[tid * 4 + 0], p1 = wsums[tid * 4 + 1];
                float2 p2 = wsums[tid * 4 + 2], p3 = wsums[tid * 4 + 3];
                psum[(size_t)(row0 + tid) * 8 + bx] =
                    make_float2(p0.x + p1.x + p2.x + p3.x, p0.y + p1.y + p2.y + p3.y);
            }
        }
    } else {   // EPI 1: LN-folded classifier output, stats from psum
#pragma unroll
        for (int i = 0; i < 4; ++i) {
            int rbase = row0 + wm * 64 + i * 16 + g * 4;
            float2 mr[4];
#pragma unroll
            for (int r = 0; r < 4; ++r) {
                const floatx4* pp = (const floatx4*)(psum + (size_t)(rbase + r) * 8);
                floatx4 q0 = pp[0], q1 = pp[1], q2 = pp[2], q3 = pp[3];
                float S  = (q0[0] + q0[2]) + (q1[0] + q1[2]) + (q2[0] + q2[2]) + (q3[0] + q3[2]);
                float S2 = (q0[1] + q0[3]) + (q1[1] + q1[3]) + (q2[1] + q2[3]) + (q3[1] + q3[3]);
                float mu = S * (1.f / 2048.f);
                float var = S2 * (1.f / 2048.f) - mu * mu;
                mr[r] = make_float2(mu, rsqrtf(var + 1e-5f));
            }
#pragma unroll
            for (int j = 0; j < NJ; ++j) {
                int col = col0 + wn * (16 * NJ) + j * 16 + fr;
                if (col < ncols) {
                    float ws = wsum[col];
                    float ccv = bias0[col];
                    float* O = (float*)Cout;
#pragma unroll
                    for (int r = 0; r < 4; ++r)
                        O[(size_t)(rbase + r) * ncols + col] =
                            mr[r].y * (acc[i][j][r] - mr[r].x * ws) + ccv;
                }
            }
        }
    }
}

extern "C" void kernel_launch(void* const* d_in, const int* in_sizes, int n_in,
                              void* d_out, int out_size, void* d_ws, size_t ws_size,
                              hipStream_t stream) {
    const float* x   = (const float*)d_in[0];
    const float* W0  = (const float*)d_in[1];
    const float* bi0 = (const float*)d_in[2];
    const float* bh0 = (const float*)d_in[3];
    const float* W1  = (const float*)d_in[4];
    const float* bi1 = (const float*)d_in[5];
    const float* bh1 = (const float*)d_in[6];
    const float* lng = (const float*)d_in[7];
    const float* lnb = (const float*)d_in[8];
    const float* fcW = (const float*)d_in[9];
    const float* fcb = (const float*)d_in[10];
    float* out = (float*)d_out;

    char* w = (char*)d_ws;
    unsigned short* xb   = (unsigned short*)(w);                  // 4096x4096 bf16
    unsigned short* w0b  = (unsigned short*)(w + 33554432ull);    // 2048x4096 bf16
    unsigned short* w1b  = (unsigned short*)(w + 50331648ull);    // 2048x2048 bf16
    unsigned short* h1   = (unsigned short*)(w + 58720256ull);    // 4096x2048 bf16
    unsigned short* h2   = (unsigned short*)(w + 75497472ull);    // 4096x2048 bf16
    unsigned short* weff = (unsigned short*)(w + 92274688ull);    // 1024x2048 bf16
    float* cc            = (float*)(w + 96468992ull);             // 1024 f32
    float* wsum          = (float*)(w + 96473088ull);             // 1024 f32
    float2* psum         = (float2*)(w + 96477184ull);            // 4096x8 float2 (512KB)

    const int SHM0 = 3 * (16384 + 4 * 8192);  // 147456
    const int SHM1 = 3 * (16384 + 2 * 8192);  // 98304
    (void)hipFuncSetAttribute((const void*)gemm_rp<0, 4>,
                              hipFuncAttributeMaxDynamicSharedMemorySize, SHM0);
    (void)hipFuncSetAttribute((const void*)gemm_rp<2, 4>,
                              hipFuncAttributeMaxDynamicSharedMemorySize, SHM0);
    (void)hipFuncSetAttribute((const void*)gemm_rp<1, 2>,
                              hipFuncAttributeMaxDynamicSharedMemorySize, SHM1);

    // prep: cvt x/W0/W1 -> bf16 and build Weff/cc/wsum, single dispatch
    prep_kernel<<<15360, 256, 0, stream>>>(x, xb, W0, w0b, W1, w1b,
                                           fcW, lng, lnb, fcb, weff, cc, wsum);
    // h1 = tanh(x @ W0^T + b_ih0 + b_hh0)
    gemm_rp<0, 4><<<dim3(8, 32), 512, SHM0, stream>>>(xb, w0b, 4096, 2048, 4096,
                                                      bi0, bh0, h1, 2048, nullptr, nullptr);
    // h2 = tanh(h1 @ W1^T + b_ih1 + b_hh1); LN partial sums -> psum
    gemm_rp<2, 4><<<dim3(8, 32), 512, SHM0, stream>>>(h1, w1b, 4096, 2048, 2048,
                                                      bi1, bh1, h2, 2048, psum, nullptr);
    // out = r*(h2 @ Weff^T - mu*wsum) + cc   (LN stats inline from psum)
    gemm_rp<1, 2><<<dim3(8, 32), 512, SHM1, stream>>>(h2, weff, 4096, 1024, 2048,
                                                      cc, nullptr, out, 1000, psum, wsum);
}

// Round 13
// 170.261 us; speedup vs baseline: 1.0133x; 1.0133x over previous
//
#include <hip/hip_runtime.h>
#include <hip/hip_bf16.h>

typedef __attribute__((ext_vector_type(8))) unsigned short ushort8;
typedef __attribute__((ext_vector_type(8))) __bf16 bf16x8;
typedef __attribute__((ext_vector_type(4))) float f32x4;
typedef __attribute__((ext_vector_type(4))) float floatx4;

__device__ __forceinline__ unsigned short f2bf(float f) {
    unsigned u = __builtin_bit_cast(unsigned, f);
    u += 0x7fffu + ((u >> 16) & 1u);   // RNE
    return (unsigned short)(u >> 16);
}
__device__ __forceinline__ float bf2f(unsigned short h) {
    unsigned u = ((unsigned)h) << 16;
    return __builtin_bit_cast(float, u);
}

__device__ __forceinline__ void gload_lds16(const void* g, void* l) {
    __builtin_amdgcn_global_load_lds(
        (const __attribute__((address_space(1))) void*)g,
        (__attribute__((address_space(3))) void*)l,
        16, 0, 0);
}

#define BAR()   asm volatile("s_barrier" ::: "memory")
#define VMW0()  asm volatile("s_waitcnt vmcnt(0)" ::: "memory")

// ===== merged prep: 3 f32->bf16 converts + Weff, one dispatch ============
// blocks [0,8192)      : cvt x      (2097152 x 8 elems)
// blocks [8192,12288)  : cvt W0     (1048576 x 8)
// blocks [12288,14336) : cvt W1     (524288 x 8)
// blocks [14336,15360) : weff row o = b - 14336
__global__ __launch_bounds__(256) void prep_kernel(
        const float* __restrict__ x,   unsigned short* __restrict__ xb,
        const float* __restrict__ W0,  unsigned short* __restrict__ w0b,
        const float* __restrict__ W1,  unsigned short* __restrict__ w1b,
        const float* __restrict__ fcW, const float* __restrict__ lng,
        const float* __restrict__ lnb, const float* __restrict__ fcb,
        unsigned short* __restrict__ weff, float* __restrict__ cc,
        float* __restrict__ wsum) {
    const int b = blockIdx.x;
    const int tid = threadIdx.x;
    __shared__ float red[4], redw[4];

    if (b < 14336) {
        const float* in; unsigned short* out; int i;
        if (b < 8192)       { in = x;  out = xb;  i = b * 256 + tid; }
        else if (b < 12288) { in = W0; out = w0b; i = (b - 8192) * 256 + tid; }
        else                { in = W1; out = w1b; i = (b - 12288) * 256 + tid; }
        floatx4 a = ((const floatx4*)in)[2 * i];
        floatx4 c = ((const floatx4*)in)[2 * i + 1];
        ushort8 o;
#pragma unroll
        for (int j = 0; j < 4; ++j) { o[j] = f2bf(a[j]); o[4 + j] = f2bf(c[j]); }
        ((ushort8*)out)[i] = o;
        return;
    }

    const int o = b - 14336;
    if (o >= 1000) {
        ushort8 z = {0, 0, 0, 0, 0, 0, 0, 0};
        ((ushort8*)(weff + (size_t)o * 2048))[tid] = z;
        if (tid == 0) { cc[o] = 0.f; wsum[o] = 0.f; }
        return;
    }
    const float* wrow = fcW + (size_t)o * 4096;
    int j0 = tid * 8;
    floatx4 wa  = *(const floatx4*)(wrow + j0);
    floatx4 wb  = *(const floatx4*)(wrow + j0 + 4);
    floatx4 wa2 = *(const floatx4*)(wrow + 2048 + j0);
    floatx4 wb2 = *(const floatx4*)(wrow + 2048 + j0 + 4);
    floatx4 ga  = *(const floatx4*)(lng + j0);
    floatx4 gb  = *(const floatx4*)(lng + j0 + 4);
    floatx4 ga2 = *(const floatx4*)(lng + 2048 + j0);
    floatx4 gb2 = *(const floatx4*)(lng + 2048 + j0 + 4);
    floatx4 ba  = *(const floatx4*)(lnb + j0);
    floatx4 bb  = *(const floatx4*)(lnb + j0 + 4);
    floatx4 ba2 = *(const floatx4*)(lnb + 2048 + j0);
    floatx4 bb2 = *(const floatx4*)(lnb + 2048 + j0 + 4);
    ushort8 o8;
    float acc = 0.f, ws = 0.f;
#pragma unroll
    for (int j = 0; j < 4; ++j) {
        o8[j] = f2bf(ga[j] * wa[j] + ga2[j] * wa2[j]);
        acc += ba[j] * wa[j] + ba2[j] * wa2[j];
        ws  += bf2f(o8[j]);
        o8[4 + j] = f2bf(gb[j] * wb[j] + gb2[j] * wb2[j]);
        acc += bb[j] * wb[j] + bb2[j] * wb2[j];
        ws  += bf2f(o8[4 + j]);
    }
    ((ushort8*)(weff + (size_t)o * 2048))[tid] = o8;
#pragma unroll
    for (int d = 32; d; d >>= 1) { acc += __shfl_down(acc, d); ws += __shfl_down(ws, d); }
    if ((tid & 63) == 0) { red[tid >> 6] = acc; redw[tid >> 6] = ws; }
    __syncthreads();
    if (tid == 0) {
        cc[o] = fcb[o] + red[0] + red[1] + red[2] + red[3];
        wsum[o] = redw[0] + redw[1] + redw[2] + redw[3];
    }
}

// -------- row LN stats: mur[row] = {mu, rsqrt(var+eps)} over h2 row -------
__global__ __launch_bounds__(256) void ln_stats(const unsigned short* __restrict__ h2,
                                                float2* __restrict__ mur) {
    int row = blockIdx.x, tid = threadIdx.x;
    ushort8 v = ((const ushort8*)(h2 + (size_t)row * 2048))[tid];
    float s = 0.f, s2 = 0.f;
#pragma unroll
    for (int j = 0; j < 8; ++j) { float f = bf2f(v[j]); s += f; s2 += f * f; }
#pragma unroll
    for (int d = 32; d; d >>= 1) { s += __shfl_down(s, d); s2 += __shfl_down(s2, d); }
    __shared__ float rs_[4], rs2_[4];
    if ((tid & 63) == 0) { rs_[tid >> 6] = s; rs2_[tid >> 6] = s2; }
    __syncthreads();
    if (tid == 0) {
        float S = rs_[0] + rs_[1] + rs_[2] + rs_[3];
        float S2 = rs2_[0] + rs2_[1] + rs2_[2] + rs2_[3];
        float mu = S * (1.f / 2048.f);
        float var = S2 * (1.f / 2048.f) - mu * mu;
        mur[row] = make_float2(mu, rsqrtf(var + 1e-5f));
    }
}

// == reg-pipelined bf16 GEMM: C[M,N] = A[M,K]*B[N,K]^T, BK=64, 3 LDS bufs ==
// BM=128, BN=64*NJ, 512 threads (8 waves 2M x 4N), per-wave C = 64 x 16*NJ.
// Cross-tile register double-buffer; counted vmcnt keeps one tile's stage
// loads in flight across the barrier. 128B rows, byte ^= (row&7)<<4 swizzle
// (0 conflicts measured). Best-known structure (r6/r11: gemm1 78us, 880 TF).
// EPI 0: bf16 out = tanh(acc + bias0[n] + bias1[n]), stride N
// EPI 1: f32 out = mur[row].y*(acc - mur[row].x*wsum[col]) + bias0[col]
template <int EPI, int NJ>
__global__ __launch_bounds__(512, 2) void gemm_rp(const unsigned short* __restrict__ A,
                                                  const unsigned short* __restrict__ B,
                                                  int M, int N, int K,
                                                  const float* __restrict__ bias0,
                                                  const float* __restrict__ bias1,
                                                  void* __restrict__ Cout, int ncols,
                                                  const float2* __restrict__ mur,
                                                  const float* __restrict__ wsum) {
    extern __shared__ char smem[];
    constexpr int BUFSZ = 16384 + NJ * 8192;   // A (16KB) + B (NJ*8KB), BK=64
    const int tid = threadIdx.x;
    const int lane = tid & 63, wid = tid >> 6;
    const int wm = wid >> 2, wn = wid & 3;      // 2 x 4 wave grid
    const int fr = lane & 15, g = lane >> 4;

    // XCD-aware bijective swizzle (nwg % 8 == 0 for all our launches)
    const int nwg = gridDim.x * gridDim.y;
    const int fid = blockIdx.y * gridDim.x + blockIdx.x;
    const int cpx = nwg >> 3;
    const int sw = (fid & 7) * cpx + (fid >> 3);
    const int bx = sw % gridDim.x, by = sw / gridDim.x;
    const int row0 = by * 128, col0 = bx * (64 * NJ);

    const int tg = tid >> 3;
    const int tcE = ((tid & 7) ^ (tg & 7)) * 8;

    auto stage = [&](int kt, char* buf) {
#pragma unroll
        for (int r = 0; r < 2; ++r)
            gload_lds16(A + (size_t)(row0 + r * 64 + tg) * K + kt * 64 + tcE,
                        buf + r * 8192 + wid * 1024);
#pragma unroll
        for (int rr = 0; rr < NJ; ++rr)
            gload_lds16(B + (size_t)(col0 + rr * 64 + tg) * K + kt * 64 + tcE,
                        buf + 16384 + rr * 8192 + wid * 1024);
    };

    const int xorv = (fr & 7) << 4;
    auto readFrags = [&](bf16x8 (&fa)[4][2], bf16x8 (&fb)[NJ][2], const char* buf) {
#pragma unroll
        for (int m = 0; m < 4; ++m)
#pragma unroll
            for (int kh = 0; kh < 2; ++kh)
                fa[m][kh] = __builtin_bit_cast(bf16x8, *(const ushort8*)(
                    buf + (wm * 64 + m * 16 + fr) * 128 + ((kh * 64 + g * 16) ^ xorv)));
#pragma unroll
        for (int n = 0; n < NJ; ++n)
#pragma unroll
            for (int kh = 0; kh < 2; ++kh)
                fb[n][kh] = __builtin_bit_cast(bf16x8, *(const ushort8*)(
                    buf + 16384 + (wn * (16 * NJ) + n * 16 + fr) * 128 + ((kh * 64 + g * 16) ^ xorv)));
    };

    f32x4 acc[4][NJ];
#pragma unroll
    for (int i = 0; i < 4; ++i)
#pragma unroll
        for (int j = 0; j < NJ; ++j) acc[i][j] = f32x4{0.f, 0.f, 0.f, 0.f};

    auto domfma = [&](bf16x8 (&fa)[4][2], bf16x8 (&fb)[NJ][2]) {
        __builtin_amdgcn_s_setprio(1);
#pragma unroll
        for (int m = 0; m < 4; ++m)
#pragma unroll
            for (int n = 0; n < NJ; ++n)
#pragma unroll
                for (int kh = 0; kh < 2; ++kh)
                    acc[m][n] = __builtin_amdgcn_mfma_f32_16x16x32_bf16(fa[m][kh], fb[n][kh], acc[m][n], 0, 0, 0);
        __builtin_amdgcn_s_setprio(0);
    };

    bf16x8 aX[4][2], bX[NJ][2], aY[4][2], bY[NJ][2];

    stage(0, smem); stage(1, smem + BUFSZ);
    if constexpr (NJ == 4) { asm volatile("s_waitcnt vmcnt(6)" ::: "memory"); }
    else                   { asm volatile("s_waitcnt vmcnt(4)" ::: "memory"); }
    BAR();
    readFrags(aX, bX, smem);

    const int NT = K >> 6;   // always even here
    for (int t = 0; t < NT; t += 2) {
        if (t + 2 < NT) {
            stage(t + 2, smem + ((t + 2) % 3) * BUFSZ);
            if constexpr (NJ == 4) { asm volatile("s_waitcnt vmcnt(6)" ::: "memory"); }
            else                   { asm volatile("s_waitcnt vmcnt(4)" ::: "memory"); }
        } else {
            VMW0();
        }
        BAR();
        readFrags(aY, bY, smem + ((t + 1) % 3) * BUFSZ);
        domfma(aX, bX);

        if (t + 2 < NT) {
            if (t + 3 < NT) {
                stage(t + 3, smem + ((t + 3) % 3) * BUFSZ);
                if constexpr (NJ == 4) { asm volatile("s_waitcnt vmcnt(6)" ::: "memory"); }
                else                   { asm volatile("s_waitcnt vmcnt(4)" ::: "memory"); }
            } else {
                VMW0();
            }
            BAR();
            readFrags(aX, bX, smem + ((t + 2) % 3) * BUFSZ);
        }
        domfma(aY, bY);
    }

    // ---- epilogue ----
#pragma unroll
    for (int i = 0; i < 4; ++i) {
        int rbase = row0 + wm * 64 + i * 16 + g * 4;
        if (EPI == 0) {
#pragma unroll
            for (int j = 0; j < NJ; ++j) {
                int col = col0 + wn * (16 * NJ) + j * 16 + fr;
                float bsum = bias0[col] + bias1[col];
                unsigned short* O = (unsigned short*)Cout;
#pragma unroll
                for (int r = 0; r < 4; ++r)
                    O[(size_t)(rbase + r) * N + col] = f2bf(tanhf(acc[i][j][r] + bsum));
            }
        } else {
            float2 mr[4];
#pragma unroll
            for (int r = 0; r < 4; ++r) mr[r] = mur[rbase + r];
#pragma unroll
            for (int j = 0; j < NJ; ++j) {
                int col = col0 + wn * (16 * NJ) + j * 16 + fr;
                if (col < ncols) {
                    float ws = wsum[col];
                    float ccv = bias0[col];
                    float* O = (float*)Cout;
#pragma unroll
                    for (int r = 0; r < 4; ++r)
                        O[(size_t)(rbase + r) * ncols + col] =
                            mr[r].y * (acc[i][j][r] - mr[r].x * ws) + ccv;
                }
            }
        }
    }
}

extern "C" void kernel_launch(void* const* d_in, const int* in_sizes, int n_in,
                              void* d_out, int out_size, void* d_ws, size_t ws_size,
                              hipStream_t stream) {
    const float* x   = (const float*)d_in[0];
    const float* W0  = (const float*)d_in[1];
    const float* bi0 = (const float*)d_in[2];
    const float* bh0 = (const float*)d_in[3];
    const float* W1  = (const float*)d_in[4];
    const float* bi1 = (const float*)d_in[5];
    const float* bh1 = (const float*)d_in[6];
    const float* lng = (const float*)d_in[7];
    const float* lnb = (const float*)d_in[8];
    const float* fcW = (const float*)d_in[9];
    const float* fcb = (const float*)d_in[10];
    float* out = (float*)d_out;

    char* w = (char*)d_ws;
    unsigned short* xb   = (unsigned short*)(w);                  // 4096x4096 bf16
    unsigned short* w0b  = (unsigned short*)(w + 33554432ull);    // 2048x4096 bf16
    unsigned short* w1b  = (unsigned short*)(w + 50331648ull);    // 2048x2048 bf16
    unsigned short* h1   = (unsigned short*)(w + 58720256ull);    // 4096x2048 bf16
    unsigned short* h2   = (unsigned short*)(w + 75497472ull);    // 4096x2048 bf16
    unsigned short* weff = (unsigned short*)(w + 92274688ull);    // 1024x2048 bf16
    float* cc            = (float*)(w + 96468992ull);             // 1024 f32
    float* wsum          = (float*)(w + 96473088ull);             // 1024 f32
    float2* mur          = (float2*)(w + 96477184ull);            // 4096 float2

    const int SHM0 = 3 * (16384 + 4 * 8192);  // 147456
    const int SHM1 = 3 * (16384 + 2 * 8192);  // 98304
    (void)hipFuncSetAttribute((const void*)gemm_rp<0, 4>,
                              hipFuncAttributeMaxDynamicSharedMemorySize, SHM0);
    (void)hipFuncSetAttribute((const void*)gemm_rp<1, 2>,
                              hipFuncAttributeMaxDynamicSharedMemorySize, SHM1);

    // prep: cvt x/W0/W1 -> bf16 and build Weff/cc/wsum, single dispatch
    prep_kernel<<<15360, 256, 0, stream>>>(x, xb, W0, w0b, W1, w1b,
                                           fcW, lng, lnb, fcb, weff, cc, wsum);
    // h1 = tanh(x @ W0^T + b_ih0 + b_hh0)
    gemm_rp<0, 4><<<dim3(8, 32), 512, SHM0, stream>>>(xb, w0b, 4096, 2048, 4096,
                                                      bi0, bh0, h1, 2048, nullptr, nullptr);
    // h2 = tanh(h1 @ W1^T + b_ih1 + b_hh1)
    gemm_rp<0, 4><<<dim3(8, 32), 512, SHM0, stream>>>(h1, w1b, 4096, 2048, 2048,
                                                      bi1, bh1, h2, 2048, nullptr, nullptr);
    // per-row LN stats of h2 (concat duplicates -> stats over h2 row)
    ln_stats<<<4096, 256, 0, stream>>>(h2, mur);
    // out = r*(h2 @ Weff^T - mu*wsum) + cc   (LN folded into epilogue)
    gemm_rp<1, 2><<<dim3(8, 32), 512, SHM1, stream>>>(h2, weff, 4096, 1024, 2048,
                                                      cc, nullptr, out, 1000, mur, wsum);
}